// Round 5
// baseline (72.659 us; speedup 1.0000x reference)
//
#include <hip/hip_runtime.h>
#include <hip/hip_bf16.h>

typedef __bf16 bf16_t;
typedef __bf16 bf16x8 __attribute__((ext_vector_type(8)));
typedef __bf16 bf16x4 __attribute__((ext_vector_type(4)));
typedef float  f32x4  __attribute__((ext_vector_type(4)));

#define MFMA_BF16(A, B, C) __builtin_amdgcn_mfma_f32_16x16x32_bf16((A), (B), (C), 0, 0, 0)

#define BATCH 8
#define SEQ   2048
#define EMB   1024
#define HEAD  64

typedef __attribute__((address_space(3))) void as3_void;
typedef const __attribute__((address_space(1))) void as1_void;
#define GLOAD_LDS16(g, l) \
  __builtin_amdgcn_global_load_lds((as1_void*)(g), (as3_void*)(l), 16, 0, 0)

// ---------------------------------------------------------------------------
// Kernel 0: W [1024][64] fp32 x3 -> WT bf16 [192][1024] (transposed),
// softmax scale 1/32 folded into Wq.
// ---------------------------------------------------------------------------
__global__ __launch_bounds__(256) void wtrans_kernel(
    const float* __restrict__ Wq, const float* __restrict__ Wk,
    const float* __restrict__ Wv, bf16_t* __restrict__ WT)
{
  __shared__ float tile[64][65];
  const int m  = blockIdx.x >> 4;
  const int kt = blockIdx.x & 15;
  const float* W = (m == 0) ? Wq : (m == 1) ? Wk : Wv;
  const float scale = (m == 0) ? 0.03125f : 1.0f;
  const int k0 = kt * 64;

  #pragma unroll
  for (int i = 0; i < 16; ++i) {
    int idx = i * 256 + threadIdx.x;
    int kk = idx >> 6, n = idx & 63;
    tile[kk][n] = W[(size_t)(k0 + kk) * HEAD + n];
  }
  __syncthreads();
  #pragma unroll
  for (int i = 0; i < 16; ++i) {
    int idx = i * 256 + threadIdx.x;
    int n = idx >> 6, kk = idx & 63;
    WT[((size_t)m * HEAD + n) * EMB + k0 + kk] = (bf16_t)(tile[kk][n] * scale);
  }
}

// ---------------------------------------------------------------------------
// Kernel 1: qkv v5 — high-occupancy K-split with single-buffer B chunks.
// 1024 blocks x 4 waves; block = 16 rows x 192 cols; K = 8 chunks x 128;
// wave w computes k-slice w (32 wide) of every chunk -> partials reduced once
// at the end via LDS (aliased onto the B buffer, barrier-protected).
//   B chunk: 192 rows x 128 k bf16 = 48 KB, staged via 12 global_load_lds
//   per wave, source pre-swizzled (rule #21), reads XOR-swizzled (T2).
//   x: 2 float4/chunk/wave straight to regs (64 KB/block total, HBM once).
// LDS 50176 B -> 3 blocks/CU = 12 waves/CU; 2 barriers per chunk (16 total).
// ---------------------------------------------------------------------------
__global__ __launch_bounds__(256, 3) void qkv_kernel(
    const float* __restrict__ x, const bf16_t* __restrict__ WT,
    bf16_t* __restrict__ qo, bf16_t* __restrict__ ko, bf16_t* __restrict__ vT)
{
  __shared__ char lds[50176];                    // Bs [192][256B] / red [4][16][196] f32
  bf16_t* Bs = (bf16_t*)lds;
  float*  red = (float*)lds;

  const int tid  = threadIdx.x;
  const int lane = tid & 63;
  const int wave = tid >> 6;
  const int l15 = lane & 15, l4 = lane >> 4;
  const int r0 = blockIdx.x * 16;

  // x: lane -> row r0+l15, k = wave*32 + l4*8 within each chunk
  const float* xr = x + (size_t)(r0 + l15) * EMB + wave * 32 + l4 * 8;

  // B DMA: instr g = wave*12+j covers rows 4g..4g+3; lane -> row 4g+(lane>>4),
  // LDS col-bytes (lane&15)*16 (linear dest). Source col pre-swizzled:
  //   off(g) = ((lane&15)*16) ^ ((lane>>4)*16) ^ ((g&1)<<6)
  // so that LDS[row][c] = WT[row][c ^ ((row&7)<<4)]  (XOR bits 4..6).
  const int base_off = ((lane & 15) * 16) ^ ((lane >> 4) * 16);
  const int rsub = lane >> 4;

  f32x4 acc[12];
  #pragma unroll
  for (int i = 0; i < 12; ++i) acc[i] = (f32x4){0.f, 0.f, 0.f, 0.f};

  // read-side swizzle for this lane (row&7 == l15&7 since rows are nf*16+l15)
  const int rswz = (l15 & 7) << 4;
  const int kbyte = ((wave * 64 + l4 * 16) ^ rswz);     // within 256B row

  for (int kc = 0; kc < 8; ++kc) {
    // x loads for this chunk (regs; latency overlaps barrier + DMA issue)
    float4 xf0 = *(const float4*)(xr + kc * 128);
    float4 xf1 = *(const float4*)(xr + kc * 128 + 4);

    if (kc) __syncthreads();                     // all waves done reading Bs

    // stage B chunk: 12 DMA instrs per wave
    #pragma unroll
    for (int j = 0; j < 12; ++j) {
      const int g = wave * 12 + j;
      const int row = 4 * g + rsub;
      const char* src = (const char*)WT + (size_t)row * 2048 + kc * 256
                        + (base_off ^ ((g & 1) << 6));
      GLOAD_LDS16(src, (char*)Bs + g * 1024);
    }
    asm volatile("s_waitcnt vmcnt(0)" ::: "memory");
    __syncthreads();                             // all DMAs visible

    // compute: A-frag from regs, 12 B-frags from LDS, 12 MFMA
    bf16x8 a;
    a[0] = (bf16_t)xf0.x; a[1] = (bf16_t)xf0.y; a[2] = (bf16_t)xf0.z; a[3] = (bf16_t)xf0.w;
    a[4] = (bf16_t)xf1.x; a[5] = (bf16_t)xf1.y; a[6] = (bf16_t)xf1.z; a[7] = (bf16_t)xf1.w;
    #pragma unroll
    for (int nf = 0; nf < 12; ++nf) {
      bf16x8 b = *(const bf16x8*)((const char*)Bs + (nf * 16 + l15) * 256 + kbyte);
      acc[nf] = MFMA_BF16(a, b, acc[nf]);
    }
  }

  __syncthreads();                               // done with Bs -> alias as red

  // partials -> LDS. D layout: row = l4*4+i, col = nf*16+l15 (m89-verified).
  #pragma unroll
  for (int nf = 0; nf < 12; ++nf)
    #pragma unroll
    for (int i = 0; i < 4; ++i)
      red[((size_t)wave * 16 + l4 * 4 + i) * 196 + nf * 16 + l15] = acc[nf][i];
  __syncthreads();

  const int t = threadIdx.x;
  // q,k: thread -> (row = t>>4, cols (t&15)+16j), coalesced row-major stores.
  {
    const int r = t >> 4, c0 = t & 15;
    const size_t grow = (size_t)r0 + r;
    #pragma unroll
    for (int j = 0; j < 4; ++j) {
      const int c = c0 + 16 * j;
      float v = red[(0 * 16 + r) * 196 + c] + red[(1 * 16 + r) * 196 + c]
              + red[(2 * 16 + r) * 196 + c] + red[(3 * 16 + r) * 196 + c];
      qo[grow * HEAD + c] = (bf16_t)v;
    }
    #pragma unroll
    for (int j = 4; j < 8; ++j) {
      const int c = c0 + 16 * j;
      float v = red[(0 * 16 + r) * 196 + c] + red[(1 * 16 + r) * 196 + c]
              + red[(2 * 16 + r) * 196 + c] + red[(3 * 16 + r) * 196 + c];
      ko[grow * HEAD + (c - 64)] = (bf16_t)v;
    }
  }
  // v transposed: thread -> (tloc = base + (t&15), h = (t>>4)*4+jj).
  {
    const int r2 = t & 15;
    const int b = r0 >> 11;                      // 16-row tile never crosses batch
    const int tloc = (r0 & 2047) + r2;
    #pragma unroll
    for (int jj = 0; jj < 4; ++jj) {
      const int h = (t >> 4) * 4 + jj;
      const int c = 128 + h;
      float v = red[(0 * 16 + r2) * 196 + c] + red[(1 * 16 + r2) * 196 + c]
              + red[(2 * 16 + r2) * 196 + c] + red[(3 * 16 + r2) * 196 + c];
      vT[((size_t)b * HEAD + h) * SEQ + tloc] = (bf16_t)v;
    }
  }
}

// ---------------------------------------------------------------------------
// Kernel 2: attn — strip-PAIRED blocks, 8 waves, 4-way K-split (unchanged).
// ---------------------------------------------------------------------------
__global__ __launch_bounds__(512, 4) void attn_kernel(
    const bf16_t* __restrict__ q, const bf16_t* __restrict__ k,
    const bf16_t* __restrict__ vT, float* __restrict__ out)
{
  __shared__ bf16_t P[8][16][72];
  __shared__ float olds[8][16][68];
  __shared__ float lsums[8][16];
  const int lane = threadIdx.x & 63;
  const int wave = threadIdx.x >> 6;
  const int l15 = lane & 15, l4 = lane >> 4;
  const int batch = blockIdx.x & 7;
  const int pair  = blockIdx.x >> 3;
  const int strip = (wave < 4) ? pair : (127 - pair);
  const int wsub  = wave & 3;
  const int qrow  = strip * 16;

  const bf16_t* qb = q  + ((size_t)batch * SEQ + qrow) * HEAD;
  const bf16_t* kb = k  + (size_t)batch * SEQ * HEAD;
  const bf16_t* vb = vT + (size_t)batch * HEAD * SEQ;

  bf16x8 aq0 = *(const bf16x8*)(qb + (size_t)l15 * HEAD + l4 * 8);
  bf16x8 aq1 = *(const bf16x8*)(qb + (size_t)l15 * HEAD + 32 + l4 * 8);

  f32x4 o[4];
  #pragma unroll
  for (int i = 0; i < 4; ++i) o[i] = (f32x4){0.f, 0.f, 0.f, 0.f};
  float lsum[4] = {0.f, 0.f, 0.f, 0.f};

  const int ntiles = (qrow >> 6) + 1;
  for (int t = wsub; t < ntiles; t += 4) {
    const int kv0 = t * 64;

    bf16x8 v0[4], v1[4];
    #pragma unroll
    for (int nf = 0; nf < 4; ++nf) {
      const bf16_t* vp = vb + (size_t)(nf * 16 + l15) * SEQ + kv0 + l4 * 8;
      v0[nf] = *(const bf16x8*)vp;
      v1[nf] = *(const bf16x8*)(vp + 32);
    }

    f32x4 s[4];
    #pragma unroll
    for (int nf = 0; nf < 4; ++nf) s[nf] = (f32x4){0.f, 0.f, 0.f, 0.f};
    #pragma unroll
    for (int nf = 0; nf < 4; ++nf) {
      const bf16_t* kp = kb + (size_t)(kv0 + nf * 16 + l15) * HEAD + l4 * 8;
      bf16x8 b0 = *(const bf16x8*)kp;
      bf16x8 b1 = *(const bf16x8*)(kp + 32);
      s[nf] = MFMA_BF16(aq0, b0, s[nf]);
      s[nf] = MFMA_BF16(aq1, b1, s[nf]);
    }

    const bool diag = (t == ntiles - 1);
    #pragma unroll
    for (int nf = 0; nf < 4; ++nf) {
      #pragma unroll
      for (int i = 0; i < 4; ++i) {
        float e = __expf(s[nf][i]);
        if (diag) {
          const int col = kv0 + nf * 16 + l15;
          const int row = qrow + l4 * 4 + i;
          e = (col <= row) ? e : 0.f;
        }
        lsum[i] += e;
        P[wave][l4 * 4 + i][nf * 16 + l15] = (bf16_t)e;
      }
    }
    asm volatile("s_waitcnt lgkmcnt(0)" ::: "memory");

    bf16x8 ap0 = *(const bf16x8*)&P[wave][l15][l4 * 8];
    bf16x8 ap1 = *(const bf16x8*)&P[wave][l15][32 + l4 * 8];
    #pragma unroll
    for (int nf = 0; nf < 4; ++nf) {
      o[nf] = MFMA_BF16(ap0, v0[nf], o[nf]);
      o[nf] = MFMA_BF16(ap1, v1[nf], o[nf]);
    }
  }

  #pragma unroll
  for (int i = 0; i < 4; ++i) {
    float v = lsum[i];
    v += __shfl_xor(v, 1);
    v += __shfl_xor(v, 2);
    v += __shfl_xor(v, 4);
    v += __shfl_xor(v, 8);
    if (l15 == 0) lsums[wave][l4 * 4 + i] = v;
  }
  #pragma unroll
  for (int nf = 0; nf < 4; ++nf)
    #pragma unroll
    for (int i = 0; i < 4; ++i)
      olds[wave][l4 * 4 + i][nf * 16 + l15] = o[nf][i];
  __syncthreads();

  {
    const int g  = threadIdx.x >> 8;
    const int tt = threadIdx.x & 255;
    const int r = tt >> 4, c0 = tt & 15;
    const int sstrip = g ? (127 - pair) : pair;
    const int w0 = g * 4;
    const float s = lsums[w0][r] + lsums[w0+1][r] + lsums[w0+2][r] + lsums[w0+3][r];
    const float rinv = 1.0f / s;
    float* ob = out + ((size_t)batch * SEQ + sstrip * 16 + r) * HEAD;
    #pragma unroll
    for (int j = 0; j < 4; ++j) {
      const int c = c0 + 16 * j;
      float v = olds[w0][r][c] + olds[w0+1][r][c] + olds[w0+2][r][c] + olds[w0+3][r][c];
      ob[c] = v * rinv;
    }
  }
}

// ---------------------------------------------------------------------------
extern "C" void kernel_launch(void* const* d_in, const int* in_sizes, int n_in,
                              void* d_out, int out_size, void* d_ws, size_t ws_size,
                              hipStream_t stream)
{
  const float* x  = (const float*)d_in[0];
  const float* Wq = (const float*)d_in[1];
  const float* Wk = (const float*)d_in[2];
  const float* Wv = (const float*)d_in[3];
  float* out = (float*)d_out;

  const size_t SZ_QKV = (size_t)BATCH * SEQ * HEAD * sizeof(bf16_t);   // 2 MiB
  if (ws_size < 3 * SZ_QKV + (size_t)192 * EMB * sizeof(bf16_t)) return;
  char* ws = (char*)d_ws;
  bf16_t* qo = (bf16_t*)(ws);
  bf16_t* ko = (bf16_t*)(ws + SZ_QKV);
  bf16_t* vT = (bf16_t*)(ws + 2 * SZ_QKV);
  bf16_t* WT = (bf16_t*)(ws + 3 * SZ_QKV);

  wtrans_kernel<<<dim3(48),   dim3(256), 0, stream>>>(Wq, Wk, Wv, WT);
  qkv_kernel  <<<dim3(1024), dim3(256), 0, stream>>>(x, WT, qo, ko, vT);
  attn_kernel <<<dim3(512),  dim3(512), 0, stream>>>(qo, ko, vT, out);
}

// Round 6
// 60.670 us; speedup vs baseline: 1.1976x; 1.1976x over previous
//
#include <hip/hip_runtime.h>
#include <hip/hip_bf16.h>

typedef __bf16 bf16_t;
typedef __bf16 bf16x8 __attribute__((ext_vector_type(8)));
typedef __bf16 bf16x4 __attribute__((ext_vector_type(4)));
typedef float  f32x4  __attribute__((ext_vector_type(4)));

#define MFMA_BF16(A, B, C) __builtin_amdgcn_mfma_f32_16x16x32_bf16((A), (B), (C), 0, 0, 0)

#define BATCH 8
#define SEQ   2048
#define EMB   1024
#define HEAD  64

typedef __attribute__((address_space(3))) void as3_void;
typedef const __attribute__((address_space(1))) void as1_void;
#define GLOAD_LDS16(g, l) \
  __builtin_amdgcn_global_load_lds((as1_void*)(g), (as3_void*)(l), 16, 0, 0)

// ---------------------------------------------------------------------------
// Kernel 0: W [1024][64] fp32 x3 -> WT bf16 [192][1024] (transposed),
// softmax scale 1/32 folded into Wq.
// ---------------------------------------------------------------------------
__global__ __launch_bounds__(256) void wtrans_kernel(
    const float* __restrict__ Wq, const float* __restrict__ Wk,
    const float* __restrict__ Wv, bf16_t* __restrict__ WT)
{
  __shared__ float tile[64][65];
  const int m  = blockIdx.x >> 4;
  const int kt = blockIdx.x & 15;
  const float* W = (m == 0) ? Wq : (m == 1) ? Wk : Wv;
  const float scale = (m == 0) ? 0.03125f : 1.0f;
  const int k0 = kt * 64;

  #pragma unroll
  for (int i = 0; i < 16; ++i) {
    int idx = i * 256 + threadIdx.x;
    int kk = idx >> 6, n = idx & 63;
    tile[kk][n] = W[(size_t)(k0 + kk) * HEAD + n];
  }
  __syncthreads();
  #pragma unroll
  for (int i = 0; i < 16; ++i) {
    int idx = i * 256 + threadIdx.x;
    int n = idx >> 6, kk = idx & 63;
    WT[((size_t)m * HEAD + n) * EMB + k0 + kk] = (bf16_t)(tile[kk][n] * scale);
  }
}

// ---------------------------------------------------------------------------
// Kernel 1: qkv v6 — BM=64 x N=192 x BK=64, 256 blocks (1/CU, no tail),
// 8 waves (2M x 4N). Wave = 32 rows x 48 cols, FULL K (no reduction).
// ALL staging via global_load_lds (A stays fp32 in LDS, cvt at read).
// Double-buffered (80 KB), 1 barrier/step, 16 steps; stage(t+1) issued at
// the top of step t so the end-of-step vmcnt(0) waits on data already
// streaming (wait == BW service time, not added latency).
// Swizzles (rule #21, both sides): A byte^=(row&7)<<5, B byte^=(row&7)<<4
// -> all LDS reads 2-way max (free, m136).
// Per-CU per-step: HBM 1575 cyc >> LDS 1344 >> MFMA 120 -> HBM-bound.
// ---------------------------------------------------------------------------
#define A_BYTES 16384     // 64 rows x 256 B (fp32 k-slice)
#define B_BYTES 24576     // 192 rows x 128 B (bf16 k-slice)
#define BUF_BYTES (A_BYTES + B_BYTES)

__global__ __launch_bounds__(512, 2) void qkv_kernel(
    const float* __restrict__ x, const bf16_t* __restrict__ WT,
    bf16_t* __restrict__ qo, bf16_t* __restrict__ ko, bf16_t* __restrict__ vT)
{
  __shared__ char lds[2][BUF_BYTES];

  const int tid  = threadIdx.x;
  const int lane = tid & 63;
  const int wave = tid >> 6;
  const int l15 = lane & 15, l4 = lane >> 4;
  const int wm = wave >> 2, wn = wave & 3;
  const int rowbase = blockIdx.x * 64;

  // A-DMA lane geometry: instr g covers rows 4g..4g+3, lane -> row 4g+(l>>4),
  // dest row-byte (l&15)*16 (linear). Source pre-swizzled with the READ xor:
  // koff = ((l&15)*16) ^ ((row&7)<<5), row&7 = ((g&1)<<2)|(l>>4).
  const int a_lrow  = lane >> 4;
  const int a_koff0 = (lane & 15) * 16;
  // B-DMA: instr g covers rows 8g..8g+7, lane -> row 8g+(l>>3),
  // koff = ((l&7)*16) ^ ((l>>3)<<4)  (row&7 == l>>3, g-independent).
  const int b_lrow = lane >> 3;
  const int b_koff = ((lane & 7) * 16) ^ ((lane >> 3) << 4);

  // read-side swizzles (row&7 == l15&7 for all fragment reads)
  const int aswz = (l15 & 7) << 5;
  const int bswz = (l15 & 7) << 4;

  f32x4 acc[2][3];
  #pragma unroll
  for (int m = 0; m < 2; ++m)
    #pragma unroll
    for (int n = 0; n < 3; ++n) acc[m][n] = (f32x4){0.f, 0.f, 0.f, 0.f};

  // ---- stage step t into buf: 2 A-instrs + 3 B-instrs per wave
#define STAGE(t, buf)                                                          \
  {                                                                            \
    _Pragma("unroll")                                                          \
    for (int j = 0; j < 2; ++j) {                                              \
      const int g = 2 * wave + j;                                              \
      const int row = 4 * g + a_lrow;                                          \
      const int koff = a_koff0 ^ (((((g & 1) << 2) | a_lrow)) << 5);           \
      const char* src = (const char*)x + (size_t)(rowbase + row) * 4096        \
                        + (size_t)(t) * 256 + koff;                            \
      GLOAD_LDS16(src, (buf) + g * 1024);                                      \
    }                                                                          \
    _Pragma("unroll")                                                          \
    for (int j = 0; j < 3; ++j) {                                              \
      const int g = 3 * wave + j;                                              \
      const int row = 8 * g + b_lrow;                                          \
      const char* src = (const char*)WT + (size_t)row * 2048                   \
                        + (size_t)(t) * 128 + b_koff;                          \
      GLOAD_LDS16(src, (buf) + A_BYTES + g * 1024);                            \
    }                                                                          \
  }

  // prologue
  STAGE(0, lds[0]);
  asm volatile("s_waitcnt vmcnt(0)" ::: "memory");
  __syncthreads();

  for (int t = 0; t < 16; ++t) {
    const char* buf = lds[t & 1];
    if (t + 1 < 16) STAGE(t + 1, lds[(t + 1) & 1]);   // issue early

    const char* Ab = buf;
    const char* Bb = buf + A_BYTES;
    #pragma unroll
    for (int ksub = 0; ksub < 2; ++ksub) {
      bf16x8 afr[2];
      #pragma unroll
      for (int m = 0; m < 2; ++m) {
        const int R = wm * 32 + m * 16 + l15;
        const char* rp = Ab + R * 256 + ((ksub * 128 + l4 * 32) ^ aswz);
        f32x4 p0 = *(const f32x4*)(rp);
        f32x4 p1 = *(const f32x4*)(rp + 16);       // bit4 clear in rb ^ aswz
        bf16x8 a;
        a[0] = (bf16_t)p0.x; a[1] = (bf16_t)p0.y; a[2] = (bf16_t)p0.z; a[3] = (bf16_t)p0.w;
        a[4] = (bf16_t)p1.x; a[5] = (bf16_t)p1.y; a[6] = (bf16_t)p1.z; a[7] = (bf16_t)p1.w;
        afr[m] = a;
      }
      #pragma unroll
      for (int n = 0; n < 3; ++n) {
        const int R = wn * 48 + n * 16 + l15;
        bf16x8 b = *(const bf16x8*)(Bb + R * 128 + ((ksub * 64 + l4 * 16) ^ bswz));
        acc[0][n] = MFMA_BF16(afr[0], b, acc[0][n]);
        acc[1][n] = MFMA_BF16(afr[1], b, acc[1][n]);
      }
    }

    asm volatile("s_waitcnt vmcnt(0)" ::: "memory");  // drain t+1 DMAs
    __syncthreads();
  }
#undef STAGE

  // ---- epilogue: D row = l4*4+i, col = l15 (m89-verified); col uniform/wave
  #pragma unroll
  for (int n = 0; n < 3; ++n) {
    const int col = wn * 48 + n * 16;                 // + l15
    #pragma unroll
    for (int m = 0; m < 2; ++m) {
      const int r0 = rowbase + wm * 32 + m * 16 + l4 * 4;
      if (col < 64) {
        #pragma unroll
        for (int i = 0; i < 4; ++i)
          qo[(size_t)(r0 + i) * HEAD + col + l15] = (bf16_t)acc[m][n][i];
      } else if (col < 128) {
        #pragma unroll
        for (int i = 0; i < 4; ++i)
          ko[(size_t)(r0 + i) * HEAD + col - 64 + l15] = (bf16_t)acc[m][n][i];
      } else {
        const int h = col - 128 + l15;
        bf16x4 pk;
        #pragma unroll
        for (int i = 0; i < 4; ++i) pk[i] = (bf16_t)acc[m][n][i];
        *(bf16x4*)(vT + ((size_t)(r0 >> 11) * HEAD + h) * SEQ + (r0 & 2047)) = pk;
      }
    }
  }
}

// ---------------------------------------------------------------------------
// Kernel 2: attn — strip-PAIRED blocks, 8 waves, 4-way K-split (unchanged).
// ---------------------------------------------------------------------------
__global__ __launch_bounds__(512, 4) void attn_kernel(
    const bf16_t* __restrict__ q, const bf16_t* __restrict__ k,
    const bf16_t* __restrict__ vT, float* __restrict__ out)
{
  __shared__ bf16_t P[8][16][72];
  __shared__ float olds[8][16][68];
  __shared__ float lsums[8][16];
  const int lane = threadIdx.x & 63;
  const int wave = threadIdx.x >> 6;
  const int l15 = lane & 15, l4 = lane >> 4;
  const int batch = blockIdx.x & 7;
  const int pair  = blockIdx.x >> 3;
  const int strip = (wave < 4) ? pair : (127 - pair);
  const int wsub  = wave & 3;
  const int qrow  = strip * 16;

  const bf16_t* qb = q  + ((size_t)batch * SEQ + qrow) * HEAD;
  const bf16_t* kb = k  + (size_t)batch * SEQ * HEAD;
  const bf16_t* vb = vT + (size_t)batch * HEAD * SEQ;

  bf16x8 aq0 = *(const bf16x8*)(qb + (size_t)l15 * HEAD + l4 * 8);
  bf16x8 aq1 = *(const bf16x8*)(qb + (size_t)l15 * HEAD + 32 + l4 * 8);

  f32x4 o[4];
  #pragma unroll
  for (int i = 0; i < 4; ++i) o[i] = (f32x4){0.f, 0.f, 0.f, 0.f};
  float lsum[4] = {0.f, 0.f, 0.f, 0.f};

  const int ntiles = (qrow >> 6) + 1;
  for (int t = wsub; t < ntiles; t += 4) {
    const int kv0 = t * 64;

    bf16x8 v0[4], v1[4];
    #pragma unroll
    for (int nf = 0; nf < 4; ++nf) {
      const bf16_t* vp = vb + (size_t)(nf * 16 + l15) * SEQ + kv0 + l4 * 8;
      v0[nf] = *(const bf16x8*)vp;
      v1[nf] = *(const bf16x8*)(vp + 32);
    }

    f32x4 s[4];
    #pragma unroll
    for (int nf = 0; nf < 4; ++nf) s[nf] = (f32x4){0.f, 0.f, 0.f, 0.f};
    #pragma unroll
    for (int nf = 0; nf < 4; ++nf) {
      const bf16_t* kp = kb + (size_t)(kv0 + nf * 16 + l15) * HEAD + l4 * 8;
      bf16x8 b0 = *(const bf16x8*)kp;
      bf16x8 b1 = *(const bf16x8*)(kp + 32);
      s[nf] = MFMA_BF16(aq0, b0, s[nf]);
      s[nf] = MFMA_BF16(aq1, b1, s[nf]);
    }

    const bool diag = (t == ntiles - 1);
    #pragma unroll
    for (int nf = 0; nf < 4; ++nf) {
      #pragma unroll
      for (int i = 0; i < 4; ++i) {
        float e = __expf(s[nf][i]);
        if (diag) {
          const int col = kv0 + nf * 16 + l15;
          const int row = qrow + l4 * 4 + i;
          e = (col <= row) ? e : 0.f;
        }
        lsum[i] += e;
        P[wave][l4 * 4 + i][nf * 16 + l15] = (bf16_t)e;
      }
    }
    asm volatile("s_waitcnt lgkmcnt(0)" ::: "memory");

    bf16x8 ap0 = *(const bf16x8*)&P[wave][l15][l4 * 8];
    bf16x8 ap1 = *(const bf16x8*)&P[wave][l15][32 + l4 * 8];
    #pragma unroll
    for (int nf = 0; nf < 4; ++nf) {
      o[nf] = MFMA_BF16(ap0, v0[nf], o[nf]);
      o[nf] = MFMA_BF16(ap1, v1[nf], o[nf]);
    }
  }

  #pragma unroll
  for (int i = 0; i < 4; ++i) {
    float v = lsum[i];
    v += __shfl_xor(v, 1);
    v += __shfl_xor(v, 2);
    v += __shfl_xor(v, 4);
    v += __shfl_xor(v, 8);
    if (l15 == 0) lsums[wave][l4 * 4 + i] = v;
  }
  #pragma unroll
  for (int nf = 0; nf < 4; ++nf)
    #pragma unroll
    for (int i = 0; i < 4; ++i)
      olds[wave][l4 * 4 + i][nf * 16 + l15] = o[nf][i];
  __syncthreads();

  {
    const int g  = threadIdx.x >> 8;
    const int tt = threadIdx.x & 255;
    const int r = tt >> 4, c0 = tt & 15;
    const int sstrip = g ? (127 - pair) : pair;
    const int w0 = g * 4;
    const float s = lsums[w0][r] + lsums[w0+1][r] + lsums[w0+2][r] + lsums[w0+3][r];
    const float rinv = 1.0f / s;
    float* ob = out + ((size_t)batch * SEQ + sstrip * 16 + r) * HEAD;
    #pragma unroll
    for (int j = 0; j < 4; ++j) {
      const int c = c0 + 16 * j;
      float v = olds[w0][r][c] + olds[w0+1][r][c] + olds[w0+2][r][c] + olds[w0+3][r][c];
      ob[c] = v * rinv;
    }
  }
}

// ---------------------------------------------------------------------------
extern "C" void kernel_launch(void* const* d_in, const int* in_sizes, int n_in,
                              void* d_out, int out_size, void* d_ws, size_t ws_size,
                              hipStream_t stream)
{
  const float* x  = (const float*)d_in[0];
  const float* Wq = (const float*)d_in[1];
  const float* Wk = (const float*)d_in[2];
  const float* Wv = (const float*)d_in[3];
  float* out = (float*)d_out;

  const size_t SZ_QKV = (size_t)BATCH * SEQ * HEAD * sizeof(bf16_t);   // 2 MiB
  if (ws_size < 3 * SZ_QKV + (size_t)192 * EMB * sizeof(bf16_t)) return;
  char* ws = (char*)d_ws;
  bf16_t* qo = (bf16_t*)(ws);
  bf16_t* ko = (bf16_t*)(ws + SZ_QKV);
  bf16_t* vT = (bf16_t*)(ws + 2 * SZ_QKV);
  bf16_t* WT = (bf16_t*)(ws + 3 * SZ_QKV);

  wtrans_kernel<<<dim3(48),  dim3(256), 0, stream>>>(Wq, Wk, Wv, WT);
  qkv_kernel  <<<dim3(256), dim3(512), 0, stream>>>(x, WT, qo, ko, vT);
  attn_kernel <<<dim3(512), dim3(512), 0, stream>>>(qo, ko, vT, out);
}

// Round 7
// 56.808 us; speedup vs baseline: 1.2790x; 1.0680x over previous
//
#include <hip/hip_runtime.h>
#include <hip/hip_bf16.h>

typedef __bf16 bf16_t;
typedef __bf16 bf16x8 __attribute__((ext_vector_type(8)));
typedef __bf16 bf16x4 __attribute__((ext_vector_type(4)));
typedef float  f32x4  __attribute__((ext_vector_type(4)));

#define MFMA_BF16(A, B, C) __builtin_amdgcn_mfma_f32_16x16x32_bf16((A), (B), (C), 0, 0, 0)

#define BATCH 8
#define SEQ   2048
#define EMB   1024
#define HEAD  64

typedef __attribute__((address_space(3))) void as3_void;
typedef const __attribute__((address_space(1))) void as1_void;
#define GLOAD_LDS16(g, l) \
  __builtin_amdgcn_global_load_lds((as1_void*)(g), (as3_void*)(l), 16, 0, 0)

// ---------------------------------------------------------------------------
// Kernel 0: W [1024][64] fp32 x3 -> WT bf16 [192][1024] (transposed),
// softmax scale 1/32 folded into Wq.
// ---------------------------------------------------------------------------
__global__ __launch_bounds__(256) void wtrans_kernel(
    const float* __restrict__ Wq, const float* __restrict__ Wk,
    const float* __restrict__ Wv, bf16_t* __restrict__ WT)
{
  __shared__ float tile[64][65];
  const int m  = blockIdx.x >> 4;
  const int kt = blockIdx.x & 15;
  const float* W = (m == 0) ? Wq : (m == 1) ? Wk : Wv;
  const float scale = (m == 0) ? 0.03125f : 1.0f;
  const int k0 = kt * 64;

  #pragma unroll
  for (int i = 0; i < 16; ++i) {
    int idx = i * 256 + threadIdx.x;
    int kk = idx >> 6, n = idx & 63;
    tile[kk][n] = W[(size_t)(k0 + kk) * HEAD + n];
  }
  __syncthreads();
  #pragma unroll
  for (int i = 0; i < 16; ++i) {
    int idx = i * 256 + threadIdx.x;
    int n = idx >> 6, kk = idx & 63;
    WT[((size_t)m * HEAD + n) * EMB + k0 + kk] = (bf16_t)(tile[kk][n] * scale);
  }
}

// ---------------------------------------------------------------------------
// Kernel 1: qkv v7 — ring-4 LDS pipeline with COUNTED vmcnt + RAW s_barrier.
// v6 lesson: __syncthreads lowers to s_waitcnt vmcnt(0) + s_barrier -> every
// "prefetch" was drained at each step. Fix = T3/T4: counted vmcnt (never 0
// in main loop) + __builtin_amdgcn_s_barrier().
// BM=64 x N=192 x BK=32, 256 blocks (1/CU), 4 waves (2m x 2n), full K.
// Ring of 4 x 20KB bufs (80KB). 5 glds/wave/step -> vmcnt(10) steady.
// Hazards: interval t reads buf[t%4], DMA-writes buf[(t+3)%4] (disjoint);
// WAR one barrier apart; per-wave vmcnt+barrier => all loads visible.
// Swizzle: A (fp32,128B rows) byte^=(row&7)<<4 both sides; B (64B rows) none.
// ---------------------------------------------------------------------------
#define A_BYTES 8192      // 64 rows x 128 B (fp32 k-slice of 32)
#define B_BYTES 12288     // 192 rows x 64 B (bf16 k-slice of 32)
#define BUF_BYTES 20480

__global__ __launch_bounds__(256, 2) void qkv_kernel(
    const float* __restrict__ x, const bf16_t* __restrict__ WT,
    bf16_t* __restrict__ qo, bf16_t* __restrict__ ko, bf16_t* __restrict__ vT)
{
  __shared__ char lds[4 * BUF_BYTES];

  const int tid  = threadIdx.x;
  const int lane = tid & 63;
  const int wave = tid >> 6;
  const int l15 = lane & 15, l4 = lane >> 4;
  const int wm = wave >> 1, wn = wave & 1;
  const int rowbase = blockIdx.x * 64;

  // A DMA: instr g covers rows 8g..8g+7; lane -> row 8g+(l>>3), dest byte
  // (l&7)*16 in 128B row; source col pre-swizzled with the read XOR.
  const int a_row_sub = lane >> 3;
  const int a_src_off = (((lane & 7) ^ a_row_sub) << 4);
  // B DMA: instr g covers rows 16g..16g+15; lane -> row 16g+(l>>2),
  // byte (l&3)*16 in 64B row; no swizzle needed.
  const int b_row_sub = lane >> 2;
  const int b_src_off = (lane & 3) * 16;

  const int aswz = (l15 & 7) << 4;     // read-side XOR (row&7 == l15&7)

  f32x4 acc[2][6];
  #pragma unroll
  for (int m = 0; m < 2; ++m)
    #pragma unroll
    for (int n = 0; n < 6; ++n) acc[m][n] = (f32x4){0.f, 0.f, 0.f, 0.f};

#define STAGE(t)                                                               \
  {                                                                            \
    char* buf = lds + ((t) & 3) * BUF_BYTES;                                   \
    _Pragma("unroll")                                                          \
    for (int j = 0; j < 2; ++j) {                                              \
      const int g = wave * 2 + j;                                              \
      const int row = 8 * g + a_row_sub;                                       \
      const char* src = (const char*)x + (size_t)(rowbase + row) * 4096        \
                        + (size_t)(t) * 128 + a_src_off;                       \
      GLOAD_LDS16(src, buf + g * 1024);                                        \
    }                                                                          \
    _Pragma("unroll")                                                          \
    for (int j = 0; j < 3; ++j) {                                              \
      const int g = wave * 3 + j;                                              \
      const int row = 16 * g + b_row_sub;                                      \
      const char* src = (const char*)WT + (size_t)row * 2048                   \
                        + (size_t)(t) * 64 + b_src_off;                        \
      GLOAD_LDS16(src, buf + A_BYTES + g * 1024);                              \
    }                                                                          \
  }

#define COMPUTE(t)                                                             \
  {                                                                            \
    const char* Ab = lds + ((t) & 3) * BUF_BYTES;                              \
    const char* Bb = Ab + A_BYTES;                                             \
    bf16x8 afr[2];                                                             \
    _Pragma("unroll")                                                          \
    for (int m = 0; m < 2; ++m) {                                              \
      const int R = wm * 32 + m * 16 + l15;                                    \
      f32x4 p0 = *(const f32x4*)(Ab + R * 128 + ((l4 * 32) ^ aswz));           \
      f32x4 p1 = *(const f32x4*)(Ab + R * 128 + ((l4 * 32 + 16) ^ aswz));      \
      bf16x8 a;                                                                \
      a[0] = (bf16_t)p0.x; a[1] = (bf16_t)p0.y;                                \
      a[2] = (bf16_t)p0.z; a[3] = (bf16_t)p0.w;                                \
      a[4] = (bf16_t)p1.x; a[5] = (bf16_t)p1.y;                                \
      a[6] = (bf16_t)p1.z; a[7] = (bf16_t)p1.w;                                \
      afr[m] = a;                                                              \
    }                                                                          \
    _Pragma("unroll")                                                          \
    for (int n = 0; n < 6; ++n) {                                              \
      const int R = wn * 96 + n * 16 + l15;                                    \
      bf16x8 b = *(const bf16x8*)(Bb + R * 64 + l4 * 16);                      \
      acc[0][n] = MFMA_BF16(afr[0], b, acc[0][n]);                             \
      acc[1][n] = MFMA_BF16(afr[1], b, acc[1][n]);                             \
    }                                                                          \
  }

  // prologue: 3 steps in flight
  STAGE(0); STAGE(1); STAGE(2);
  asm volatile("s_waitcnt vmcnt(10)" ::: "memory");   // step 0 landed
  __builtin_amdgcn_s_barrier();

  #pragma unroll 4
  for (int t = 0; t < 28; ++t) {
    COMPUTE(t);
    STAGE(t + 3);
    asm volatile("s_waitcnt vmcnt(10)" ::: "memory"); // step t+1 landed
    __builtin_amdgcn_s_barrier();
  }
  // tail: t = 28..31 (stages all issued by t=28)
  COMPUTE(28); STAGE(31);
  asm volatile("s_waitcnt vmcnt(10)" ::: "memory");
  __builtin_amdgcn_s_barrier();
  COMPUTE(29);
  asm volatile("s_waitcnt vmcnt(5)" ::: "memory");
  __builtin_amdgcn_s_barrier();
  COMPUTE(30);
  asm volatile("s_waitcnt vmcnt(0)" ::: "memory");
  __builtin_amdgcn_s_barrier();
  COMPUTE(31);
#undef STAGE
#undef COMPUTE

  // epilogue: D row = l4*4+i, col = wn*96 + n*16 + l15 (m89-verified)
  #pragma unroll
  for (int n = 0; n < 6; ++n) {
    const int col = wn * 96 + n * 16;                 // wave-uniform base
    #pragma unroll
    for (int m = 0; m < 2; ++m) {
      const int r0 = rowbase + wm * 32 + m * 16 + l4 * 4;
      if (col < 64) {
        #pragma unroll
        for (int i = 0; i < 4; ++i)
          qo[(size_t)(r0 + i) * HEAD + col + l15] = (bf16_t)acc[m][n][i];
      } else if (col < 128) {
        #pragma unroll
        for (int i = 0; i < 4; ++i)
          ko[(size_t)(r0 + i) * HEAD + col - 64 + l15] = (bf16_t)acc[m][n][i];
      } else {
        const int h = col - 128 + l15;
        bf16x4 pk;
        #pragma unroll
        for (int i = 0; i < 4; ++i) pk[i] = (bf16_t)acc[m][n][i];
        *(bf16x4*)(vT + ((size_t)(r0 >> 11) * HEAD + h) * SEQ + (r0 & 2047)) = pk;
      }
    }
  }
}

// ---------------------------------------------------------------------------
// Kernel 2: attn — strip-PAIRED blocks, 8 waves, 4-way K-split,
// + T5 setprio around MFMA clusters.
// ---------------------------------------------------------------------------
__global__ __launch_bounds__(512, 4) void attn_kernel(
    const bf16_t* __restrict__ q, const bf16_t* __restrict__ k,
    const bf16_t* __restrict__ vT, float* __restrict__ out)
{
  __shared__ bf16_t P[8][16][72];
  __shared__ float olds[8][16][68];
  __shared__ float lsums[8][16];
  const int lane = threadIdx.x & 63;
  const int wave = threadIdx.x >> 6;
  const int l15 = lane & 15, l4 = lane >> 4;
  const int batch = blockIdx.x & 7;
  const int pair  = blockIdx.x >> 3;
  const int strip = (wave < 4) ? pair : (127 - pair);
  const int wsub  = wave & 3;
  const int qrow  = strip * 16;

  const bf16_t* qb = q  + ((size_t)batch * SEQ + qrow) * HEAD;
  const bf16_t* kb = k  + (size_t)batch * SEQ * HEAD;
  const bf16_t* vb = vT + (size_t)batch * HEAD * SEQ;

  bf16x8 aq0 = *(const bf16x8*)(qb + (size_t)l15 * HEAD + l4 * 8);
  bf16x8 aq1 = *(const bf16x8*)(qb + (size_t)l15 * HEAD + 32 + l4 * 8);

  f32x4 o[4];
  #pragma unroll
  for (int i = 0; i < 4; ++i) o[i] = (f32x4){0.f, 0.f, 0.f, 0.f};
  float lsum[4] = {0.f, 0.f, 0.f, 0.f};

  const int ntiles = (qrow >> 6) + 1;
  for (int t = wsub; t < ntiles; t += 4) {
    const int kv0 = t * 64;

    bf16x8 v0[4], v1[4];
    #pragma unroll
    for (int nf = 0; nf < 4; ++nf) {
      const bf16_t* vp = vb + (size_t)(nf * 16 + l15) * SEQ + kv0 + l4 * 8;
      v0[nf] = *(const bf16x8*)vp;
      v1[nf] = *(const bf16x8*)(vp + 32);
    }

    f32x4 s[4];
    #pragma unroll
    for (int nf = 0; nf < 4; ++nf) s[nf] = (f32x4){0.f, 0.f, 0.f, 0.f};
    __builtin_amdgcn_s_setprio(1);
    #pragma unroll
    for (int nf = 0; nf < 4; ++nf) {
      const bf16_t* kp = kb + (size_t)(kv0 + nf * 16 + l15) * HEAD + l4 * 8;
      bf16x8 b0 = *(const bf16x8*)kp;
      bf16x8 b1 = *(const bf16x8*)(kp + 32);
      s[nf] = MFMA_BF16(aq0, b0, s[nf]);
      s[nf] = MFMA_BF16(aq1, b1, s[nf]);
    }
    __builtin_amdgcn_s_setprio(0);

    const bool diag = (t == ntiles - 1);
    #pragma unroll
    for (int nf = 0; nf < 4; ++nf) {
      #pragma unroll
      for (int i = 0; i < 4; ++i) {
        float e = __expf(s[nf][i]);
        if (diag) {
          const int col = kv0 + nf * 16 + l15;
          const int row = qrow + l4 * 4 + i;
          e = (col <= row) ? e : 0.f;
        }
        lsum[i] += e;
        P[wave][l4 * 4 + i][nf * 16 + l15] = (bf16_t)e;
      }
    }
    asm volatile("s_waitcnt lgkmcnt(0)" ::: "memory");

    bf16x8 ap0 = *(const bf16x8*)&P[wave][l15][l4 * 8];
    bf16x8 ap1 = *(const bf16x8*)&P[wave][l15][32 + l4 * 8];
    __builtin_amdgcn_s_setprio(1);
    #pragma unroll
    for (int nf = 0; nf < 4; ++nf) {
      o[nf] = MFMA_BF16(ap0, v0[nf], o[nf]);
      o[nf] = MFMA_BF16(ap1, v1[nf], o[nf]);
    }
    __builtin_amdgcn_s_setprio(0);
  }

  #pragma unroll
  for (int i = 0; i < 4; ++i) {
    float v = lsum[i];
    v += __shfl_xor(v, 1);
    v += __shfl_xor(v, 2);
    v += __shfl_xor(v, 4);
    v += __shfl_xor(v, 8);
    if (l15 == 0) lsums[wave][l4 * 4 + i] = v;
  }
  #pragma unroll
  for (int nf = 0; nf < 4; ++nf)
    #pragma unroll
    for (int i = 0; i < 4; ++i)
      olds[wave][l4 * 4 + i][nf * 16 + l15] = o[nf][i];
  __syncthreads();

  {
    const int g  = threadIdx.x >> 8;
    const int tt = threadIdx.x & 255;
    const int r = tt >> 4, c0 = tt & 15;
    const int sstrip = g ? (127 - pair) : pair;
    const int w0 = g * 4;
    const float s = lsums[w0][r] + lsums[w0+1][r] + lsums[w0+2][r] + lsums[w0+3][r];
    const float rinv = 1.0f / s;
    float* ob = out + ((size_t)batch * SEQ + sstrip * 16 + r) * HEAD;
    #pragma unroll
    for (int j = 0; j < 4; ++j) {
      const int c = c0 + 16 * j;
      float v = olds[w0][r][c] + olds[w0+1][r][c] + olds[w0+2][r][c] + olds[w0+3][r][c];
      ob[c] = v * rinv;
    }
  }
}

// ---------------------------------------------------------------------------
extern "C" void kernel_launch(void* const* d_in, const int* in_sizes, int n_in,
                              void* d_out, int out_size, void* d_ws, size_t ws_size,
                              hipStream_t stream)
{
  const float* x  = (const float*)d_in[0];
  const float* Wq = (const float*)d_in[1];
  const float* Wk = (const float*)d_in[2];
  const float* Wv = (const float*)d_in[3];
  float* out = (float*)d_out;

  const size_t SZ_QKV = (size_t)BATCH * SEQ * HEAD * sizeof(bf16_t);   // 2 MiB
  if (ws_size < 3 * SZ_QKV + (size_t)192 * EMB * sizeof(bf16_t)) return;
  char* ws = (char*)d_ws;
  bf16_t* qo = (bf16_t*)(ws);
  bf16_t* ko = (bf16_t*)(ws + SZ_QKV);
  bf16_t* vT = (bf16_t*)(ws + 2 * SZ_QKV);
  bf16_t* WT = (bf16_t*)(ws + 3 * SZ_QKV);

  wtrans_kernel<<<dim3(48),  dim3(256), 0, stream>>>(Wq, Wk, Wv, WT);
  qkv_kernel  <<<dim3(256), dim3(256), 0, stream>>>(x, WT, qo, ko, vT);
  attn_kernel <<<dim3(512), dim3(512), 0, stream>>>(qo, ko, vT, out);
}